// Round 1
// 1449.457 us; speedup vs baseline: 1.1341x; 1.1341x over previous
//
#include <hip/hip_runtime.h>
#include <cstdint>
#include <cstddef>

// ---------------------------------------------------------------------------
// ParameterizedKnowledgeStore: out = softmax(q @ (bank@Wk+bk)^T) @ (bank@Wv+bv)
// B*S=8192 queries (Q=512), K=32768 knowledge rows, H=1024.
// R6: bank converted once; deferred normalization; R=2048 chunks.
// R7: score + pv GEMMs ported to the 256x256 / BK=64 / 8-wave 8-phase
//     counted-vmcnt schedule (T2 swizzle + T3/T4 pipeline + T5 setprio).
//     LDS 128KB double-buffered, vmcnt(6) once per K-tile (never 0 in loop),
//     raw s_barrier with compiler fences. Keys/values GEMMs unchanged.
// ---------------------------------------------------------------------------

typedef __bf16 bf16_t;
typedef __bf16 bf16x4 __attribute__((ext_vector_type(4)));
typedef __bf16 bf16x8 __attribute__((ext_vector_type(8)));
typedef _Float16 f16_t;
typedef _Float16 f16x4 __attribute__((ext_vector_type(4)));
typedef _Float16 f16x8 __attribute__((ext_vector_type(8)));
typedef float f32x4 __attribute__((ext_vector_type(4)));

#define KS   32768
#define HDIM 1024
#define QDIM 512
#define NQ   8192
#define SOFTMAX_C 90.0f

// ---------------------------------------------------------------------------
__device__ __forceinline__ void async16(const void* g, void* l) {
  __builtin_amdgcn_global_load_lds((const __attribute__((address_space(1))) void*)g,
                                   (__attribute__((address_space(3))) void*)l, 16, 0, 0);
}

// Compiler-fenced raw barrier: no vmcnt(0) drain, but no memory-op motion
// across it either (hipcc's s_barrier builtin is not a compiler fence).
__device__ __forceinline__ void barrier_f() {
  asm volatile("" ::: "memory");
  __builtin_amdgcn_s_barrier();
  asm volatile("" ::: "memory");
}

// ---------------------------------------------------------------------------
// old 128-tile staging helper (still used by keys/values GEMMs)
// ---------------------------------------------------------------------------
template <typename T>
__device__ __forceinline__ void stage_tile(const T* gbase, size_t ld, int k0,
                                           T* lds, int wave, int lane) {
  const int gp = ((lane & 3) ^ ((lane >> 3) & 3)) * 8;
  for (int c = wave; c < 8; c += 4) {
    const T* g = gbase + (size_t)(c * 16 + (lane >> 2)) * ld + (size_t)k0 + gp;
    async16((const void*)g, (void*)(lds + c * 512));
  }
}

// ---------------------------------------------------------------------------
// 256x256 8-phase core: stage one half-tile = 256 rows x 32 k (16KB),
// 2 global_load_lds_dwordx4 per thread. LDS layout per half: [256][32] elems,
// 16B-column swizzle c' = c ^ ((row>>1)&3) applied on the GLOBAL source
// (LDS written linearly) and on the ds_read side (involution).
// ---------------------------------------------------------------------------
template <typename T>
__device__ __forceinline__ void stage_half(const T* gbase, size_t ld, int gk,
                                           T* ldsbase, int wave, int lane) {
#pragma unroll
  for (int g = 0; g < 2; ++g) {
    const int slot = g * 512 + wave * 64 + lane;
    const int row = slot >> 2;
    const int cx = (slot & 3) ^ ((row >> 1) & 3);
    const T* src = gbase + (size_t)row * ld + (size_t)gk + cx * 8;
    // per-wave uniform LDS base; HW adds lane*16B
    async16((const void*)src, (void*)(ldsbase + g * 4096 + wave * 512));
  }
}

struct MF16 {
  typedef f16_t T; typedef f16x8 V8;
  static __device__ __forceinline__ f32x4 mm(V8 a, V8 b, f32x4 c) {
    return __builtin_amdgcn_mfma_f32_16x16x32_f16(a, b, c, 0, 0, 0);
  }
};
struct MBF16 {
  typedef bf16_t T; typedef bf16x8 V8;
  static __device__ __forceinline__ f32x4 mm(V8 a, V8 b, f32x4 c) {
    return __builtin_amdgcn_mfma_f32_16x16x32_bf16(a, b, c, 0, 0, 0);
  }
};

// sm: 65536 elems (128KB). buf b at b*32768: A-k0 @ +0, A-k1 @ +8192,
// B-k0 @ +16384, B-k1 @ +24576. Halves: H0=B-k0 H1=B-k1 H2=A-k0 H3=A-k1.
// Schedule per tile t (buf b=t&1): P1 reads A-k0(m0-3)+B-k0, stages T(t+1)H3;
// P2 reads A-k1(m0-3)+B-k1, stages T(t+2)H0; P3 reads A-k0(m4-7), stages
// T(t+2)H1; P4 reads A-k1(m4-7), stages T(t+2)H2; vmcnt(6) at P4 only.
template <class M>
__device__ __forceinline__ void gemm256_8p(
    const typename M::T* __restrict__ A, size_t lda,
    const typename M::T* __restrict__ B, size_t ldb,
    int kbeg, int ktiles, typename M::T* sm,
    f32x4 (&acc)[8][4], int wave, int lane) {
  typedef typename M::T T;
  typedef typename M::V8 V8;
  const int wm = wave & 1, wn = wave >> 1;
  const int qd = lane >> 4, ln = lane & 15;
  const int arow = wm * 128 + ln;
  const int brow = wn * 64 + ln;
  const int cxr = (qd ^ ((ln >> 1) & 3)) * 8;

  // prologue: T0{H0..H3}, T1{H0,H1,H2}; vmcnt(6) drains exactly T0 (8 loads)
  stage_half(B, ldb, kbeg +  0, sm + 16384, wave, lane);
  stage_half(B, ldb, kbeg + 32, sm + 24576, wave, lane);
  stage_half(A, lda, kbeg +  0, sm +     0, wave, lane);
  stage_half(A, lda, kbeg + 32, sm +  8192, wave, lane);
  stage_half(B, ldb, kbeg + 64, sm + 32768 + 16384, wave, lane);
  stage_half(B, ldb, kbeg + 96, sm + 32768 + 24576, wave, lane);
  stage_half(A, lda, kbeg + 64, sm + 32768, wave, lane);
  asm volatile("s_waitcnt vmcnt(6)" ::: "memory");
  barrier_f();

  V8 ar[4], br0[4], br1[4];
  for (int t = 0; t < ktiles; ++t) {
    const int b = t & 1;
    T* bufA = sm + b * 32768;
    T* bufB = bufA + 16384;
    T* obufA = sm + (b ^ 1) * 32768;
    const int kt = kbeg + t * 64;
    // ---- phase 1
#pragma unroll
    for (int j = 0; j < 4; ++j) br0[j] = *(const V8*)&bufB[(brow + j * 16) * 32 + cxr];
#pragma unroll
    for (int i = 0; i < 4; ++i) ar[i] = *(const V8*)&bufA[(arow + i * 16) * 32 + cxr];
    if (t + 1 < ktiles) stage_half(A, lda, kt + 96, obufA + 8192, wave, lane);
    barrier_f();
    asm volatile("s_waitcnt lgkmcnt(0)" ::: "memory");
    __builtin_amdgcn_s_setprio(1);
#pragma unroll
    for (int i = 0; i < 4; ++i)
#pragma unroll
      for (int j = 0; j < 4; ++j) acc[i][j] = M::mm(ar[i], br0[j], acc[i][j]);
    __builtin_amdgcn_s_setprio(0);
    barrier_f();
    // ---- phase 2
#pragma unroll
    for (int j = 0; j < 4; ++j) br1[j] = *(const V8*)&bufB[8192 + (brow + j * 16) * 32 + cxr];
#pragma unroll
    for (int i = 0; i < 4; ++i) ar[i] = *(const V8*)&bufA[8192 + (arow + i * 16) * 32 + cxr];
    if (t + 2 < ktiles) stage_half(B, ldb, kt + 128, bufB, wave, lane);
    barrier_f();
    asm volatile("s_waitcnt lgkmcnt(0)" ::: "memory");
    __builtin_amdgcn_s_setprio(1);
#pragma unroll
    for (int i = 0; i < 4; ++i)
#pragma unroll
      for (int j = 0; j < 4; ++j) acc[i][j] = M::mm(ar[i], br1[j], acc[i][j]);
    __builtin_amdgcn_s_setprio(0);
    barrier_f();
    // ---- phase 3 (B-k0 reused from regs)
#pragma unroll
    for (int i = 0; i < 4; ++i) ar[i] = *(const V8*)&bufA[(arow + 64 + i * 16) * 32 + cxr];
    if (t + 2 < ktiles) stage_half(B, ldb, kt + 160, bufB + 8192, wave, lane);
    barrier_f();
    asm volatile("s_waitcnt lgkmcnt(0)" ::: "memory");
    __builtin_amdgcn_s_setprio(1);
#pragma unroll
    for (int i = 0; i < 4; ++i)
#pragma unroll
      for (int j = 0; j < 4; ++j) acc[4 + i][j] = M::mm(ar[i], br0[j], acc[4 + i][j]);
    __builtin_amdgcn_s_setprio(0);
    barrier_f();
    // ---- phase 4 (B-k1 reused from regs); counted vmcnt ONCE per K-tile
#pragma unroll
    for (int i = 0; i < 4; ++i) ar[i] = *(const V8*)&bufA[8192 + (arow + 64 + i * 16) * 32 + cxr];
    if (t + 2 < ktiles) stage_half(A, lda, kt + 128, bufA, wave, lane);
    barrier_f();
    asm volatile("s_waitcnt lgkmcnt(0)" ::: "memory");
    __builtin_amdgcn_s_setprio(1);
#pragma unroll
    for (int i = 0; i < 4; ++i)
#pragma unroll
      for (int j = 0; j < 4; ++j) acc[4 + i][j] = M::mm(ar[i], br1[j], acc[4 + i][j]);
    __builtin_amdgcn_s_setprio(0);
    if (t + 2 < ktiles) { asm volatile("s_waitcnt vmcnt(6)" ::: "memory"); }
    else                { asm volatile("s_waitcnt vmcnt(0)" ::: "memory"); }
    barrier_f();
  }
}

// ---------------------------------------------------------------------------
// prep kernels
// ---------------------------------------------------------------------------
__global__ __launch_bounds__(256) void prep_q(const float* __restrict__ q,
                                              f16_t* __restrict__ qf) {
  int g = blockIdx.x * 256 + threadIdx.x;
  float4 v = *(const float4*)(q + (size_t)g * 4);
  f16x4 h;
  h[0] = (f16_t)v.x; h[1] = (f16_t)v.y; h[2] = (f16_t)v.z; h[3] = (f16_t)v.w;
  *(f16x4*)(qf + (size_t)g * 4) = h;
}

__global__ __launch_bounds__(256) void prep_bank(const float* __restrict__ bank,
                                                 f16_t* __restrict__ bh,
                                                 bf16_t* __restrict__ bb) {
  size_t g = (size_t)blockIdx.x * 256 + threadIdx.x;
  float4 v = *(const float4*)(bank + g * 4);
  f16x4 h;
  h[0] = (f16_t)v.x; h[1] = (f16_t)v.y; h[2] = (f16_t)v.z; h[3] = (f16_t)v.w;
  *(f16x4*)(bh + g * 4) = h;
  bf16x4 b;
  b[0] = (bf16_t)v.x; b[1] = (bf16_t)v.y; b[2] = (bf16_t)v.z; b[3] = (bf16_t)v.w;
  *(bf16x4*)(bb + g * 4) = b;
}

__global__ __launch_bounds__(256) void prep_wk(const float* __restrict__ Wk,
                                               f16_t* __restrict__ WkTf) {
  int t = blockIdx.x * 256 + threadIdx.x;
  int n = t >> 10, k = t & 1023;
  WkTf[t] = (f16_t)Wk[(size_t)k * QDIM + n];
}

__global__ __launch_bounds__(256) void prep_wv(const float* __restrict__ Wv,
                                               bf16_t* __restrict__ WvT) {
  int t = blockIdx.x * 256 + threadIdx.x;
  int n = t >> 10, k = t & 1023;
  WvT[t] = (bf16_t)(Wv[(size_t)k * HDIM + n]);
}

// ---------------------------------------------------------------------------
// keys GEMM (fp16, all-async): kf[32768][512] = bank_f16 @ WkTf^T + bk
// ---------------------------------------------------------------------------
__global__ __launch_bounds__(256) void keys_gemm(const f16_t* __restrict__ bh,
                                                 const f16_t* __restrict__ WkTf,
                                                 const float* __restrict__ bk,
                                                 f16_t* __restrict__ kf) {
  __shared__ alignas(16) f16_t lA[128 * 32];
  __shared__ alignas(16) f16_t lB[128 * 32];
  const int tid = threadIdx.x, lane = tid & 63, wave = tid >> 6;
  const int wm = wave & 1, wn = wave >> 1;
  const int qd = lane >> 4, ln = lane & 15;
  const int m0 = blockIdx.y * 128;
  const int n0 = blockIdx.x * 128;
  const int kqs = ((qd ^ ((ln >> 1) & 3)) << 3);
  f32x4 acc[4][4] = {};
  for (int k0 = 0; k0 < HDIM; k0 += 32) {
    stage_tile(bh + (size_t)m0 * HDIM, HDIM, k0, lA, wave, lane);
    stage_tile(WkTf + (size_t)n0 * HDIM, HDIM, k0, lB, wave, lane);
    __syncthreads();
    f16x8 af[4], bfr[4];
#pragma unroll
    for (int i = 0; i < 4; i++)
      af[i] = *(const f16x8*)&lA[(wm * 64 + i * 16 + ln) * 32 + kqs];
#pragma unroll
    for (int j = 0; j < 4; j++)
      bfr[j] = *(const f16x8*)&lB[(wn * 64 + j * 16 + ln) * 32 + kqs];
#pragma unroll
    for (int i = 0; i < 4; i++)
#pragma unroll
      for (int j = 0; j < 4; j++)
        acc[i][j] = __builtin_amdgcn_mfma_f32_16x16x32_f16(af[i], bfr[j], acc[i][j], 0, 0, 0);
    __syncthreads();
  }
#pragma unroll
  for (int j = 0; j < 4; j++) {
    const int cc = n0 + wn * 64 + j * 16 + ln;
    const float bkc = bk[cc];
#pragma unroll
    for (int i = 0; i < 4; i++) {
      const int rr = m0 + wm * 64 + i * 16 + qd * 4;
#pragma unroll
      for (int r = 0; r < 4; r++)
        kf[(size_t)(rr + r) * QDIM + cc] = (f16_t)(acc[i][j][r] + bkc);
    }
  }
}

// ---------------------------------------------------------------------------
// values GEMM (bf16, all-async, transposed out): VT[h][k] = (bank@Wv+bv)^T
// ---------------------------------------------------------------------------
__global__ __launch_bounds__(256) void values_gemm_t(const bf16_t* __restrict__ bb,
                                                     const bf16_t* __restrict__ WvT,
                                                     const float* __restrict__ bv,
                                                     bf16_t* __restrict__ VT) {
  __shared__ alignas(16) bf16_t lA[128 * 32];
  __shared__ alignas(16) bf16_t lB[128 * 32];
  const int tid = threadIdx.x, lane = tid & 63, wave = tid >> 6;
  const int wm = wave & 1, wn = wave >> 1;
  const int qd = lane >> 4, ln = lane & 15;
  const int m0 = blockIdx.x * 128;
  const int n0 = blockIdx.y * 128;
  const int kqs = ((qd ^ ((ln >> 1) & 3)) << 3);
  f32x4 acc[4][4] = {};
  for (int k0 = 0; k0 < HDIM; k0 += 32) {
    stage_tile(WvT + (size_t)m0 * HDIM, HDIM, k0, lA, wave, lane);
    stage_tile(bb + (size_t)n0 * HDIM, HDIM, k0, lB, wave, lane);
    __syncthreads();
    bf16x8 af[4], bfr[4];
#pragma unroll
    for (int i = 0; i < 4; i++)
      af[i] = *(const bf16x8*)&lA[(wm * 64 + i * 16 + ln) * 32 + kqs];
#pragma unroll
    for (int j = 0; j < 4; j++)
      bfr[j] = *(const bf16x8*)&lB[(wn * 64 + j * 16 + ln) * 32 + kqs];
#pragma unroll
    for (int i = 0; i < 4; i++)
#pragma unroll
      for (int j = 0; j < 4; j++)
        acc[i][j] = __builtin_amdgcn_mfma_f32_16x16x32_bf16(af[i], bfr[j], acc[i][j], 0, 0, 0);
    __syncthreads();
  }
#pragma unroll
  for (int i = 0; i < 4; i++) {
#pragma unroll
    for (int r = 0; r < 4; r++) {
      const int hh = m0 + wm * 64 + i * 16 + qd * 4 + r;
      const float bvc = bv[hh];
#pragma unroll
      for (int j = 0; j < 4; j++) {
        const int cc = n0 + wn * 64 + j * 16 + ln;
        VT[(size_t)hh * KS + cc] = (bf16_t)(acc[i][j][r] + bvc);
      }
    }
  }
}

// ---------------------------------------------------------------------------
// fused score GEMM (fp16, K=512, 256x256 8-phase) + softmax-exp epilogue.
// lpart[row][nblock] with nblock = KS/256 = 128 per row.
// ---------------------------------------------------------------------------
__global__ __launch_bounds__(512, 2) void score_fused_8p(
    const f16_t* __restrict__ qf, const f16_t* __restrict__ kf,
    bf16_t* __restrict__ P, float* __restrict__ lpart, int row0, int mtiles) {
  __shared__ alignas(16) f16_t sm[65536];
  const int tid = threadIdx.x, lane = tid & 63, wave = tid >> 6;
  const int bid = blockIdx.x;
  const int logical = (bid & 7) * ((int)gridDim.x >> 3) + (bid >> 3);
  const int mt_ = logical % mtiles;   // co-resident: 8m x 4n share ~3MB in L2
  const int nt_ = logical / mtiles;
  const int m0 = mt_ * 256, n0 = nt_ * 256;
  f32x4 acc[8][4] = {};
  gemm256_8p<MF16>(qf + (size_t)(row0 + m0) * QDIM, QDIM,
                   kf + (size_t)n0 * QDIM, QDIM, 0, QDIM / 64, sm, acc, wave, lane);

  const int wm = wave & 1, wn = wave >> 1;
  const int qd = lane >> 4, ln = lane & 15;
  float* ls = (float*)sm;
  if (tid < 256) ls[tid] = 0.f;
  __syncthreads();
  float rsum[8][4];
#pragma unroll
  for (int ii = 0; ii < 8; ++ii) {
    const int rr = m0 + wm * 128 + ii * 16 + qd * 4;
#pragma unroll
    for (int r = 0; r < 4; ++r) rsum[ii][r] = 0.f;
#pragma unroll
    for (int j = 0; j < 4; ++j) {
      const int cc = n0 + wn * 64 + j * 16 + ln;
#pragma unroll
      for (int r = 0; r < 4; ++r) {
        float e = __expf(acc[ii][j][r] - SOFTMAX_C);
        bf16_t pb = (bf16_t)e;
        P[(size_t)(rr + r) * KS + cc] = pb;
        rsum[ii][r] += (float)pb;
      }
    }
  }
#pragma unroll
  for (int ii = 0; ii < 8; ++ii)
#pragma unroll
    for (int r = 0; r < 4; ++r) {
      float s = rsum[ii][r];
#pragma unroll
      for (int off = 1; off < 16; off <<= 1) s += __shfl_xor(s, off);
      if (ln == 0) atomicAdd(&ls[wm * 128 + ii * 16 + qd * 4 + r], s);
    }
  __syncthreads();
  if (tid < 256)
    lpart[(size_t)(row0 + m0 + tid) * (KS / 256) + nt_] = ls[tid];
}

// ---------------------------------------------------------------------------
// PV GEMM (bf16, 256x256 8-phase): out[row][h] += P[row][k] * VT[h][k]
// Grid: bid&7 = k-split (XCD-aligned: each XCD owns one disjoint 4096-k span,
// all 32 blocks of a z sweep k in lockstep -> ~400KB live window in its L2).
// ---------------------------------------------------------------------------
__global__ __launch_bounds__(512, 2) void pv_gemm_8p(
    const bf16_t* __restrict__ P, const bf16_t* __restrict__ VT,
    float* __restrict__ Out, int row0, int mtiles) {
  __shared__ alignas(16) bf16_t sm[65536];
  const int tid = threadIdx.x, lane = tid & 63, wave = tid >> 6;
  const int bid = blockIdx.x;
  const int z = bid & 7;
  const int idx = bid >> 3;
  const int mt_ = idx % mtiles;
  const int nt_ = idx / mtiles;
  const int m0 = mt_ * 256;          // chunk-relative q rows
  const int n0 = nt_ * 256;          // h cols
  const int kbeg = z * (KS / 8);
  f32x4 acc[8][4] = {};
  gemm256_8p<MBF16>(P + (size_t)m0 * KS, KS,
                    VT + (size_t)n0 * KS, KS, kbeg, (KS / 8) / 64, sm, acc, wave, lane);

  const int wm = wave & 1, wn = wave >> 1;
  const int qd = lane >> 4, ln = lane & 15;
#pragma unroll
  for (int j = 0; j < 4; ++j) {
    const int cc = n0 + wn * 64 + j * 16 + ln;
#pragma unroll
    for (int ii = 0; ii < 8; ++ii) {
      const int rb = m0 + wm * 128 + ii * 16 + qd * 4;
#pragma unroll
      for (int r = 0; r < 4; ++r)
        atomicAdd(Out + (size_t)(row0 + rb + r) * HDIM + cc, acc[ii][j][r]);
    }
  }
}

// ---------------------------------------------------------------------------
// final: linv = 1/sum(lpart[row]); out[row] *= linv   (one block per row)
// ---------------------------------------------------------------------------
__global__ __launch_bounds__(256) void normalize(const float* __restrict__ lpart,
                                                 float* __restrict__ Out) {
  const int row = blockIdx.x;
  float s = (threadIdx.x < 128) ? lpart[(size_t)row * 128 + threadIdx.x] : 0.f;
#pragma unroll
  for (int off = 32; off; off >>= 1) s += __shfl_xor(s, off);
  __shared__ float red[4];
  if ((threadIdx.x & 63) == 0) red[threadIdx.x >> 6] = s;
  __syncthreads();
  const float linv = 1.0f / (red[0] + red[1] + red[2] + red[3]);
  float4* o = (float4*)(Out + (size_t)row * HDIM) + threadIdx.x;
  float4 v = *o;
  v.x *= linv; v.y *= linv; v.z *= linv; v.w *= linv;
  *o = v;
}

// ---------------------------------------------------------------------------
extern "C" void kernel_launch(void* const* d_in, const int* in_sizes, int n_in,
                              void* d_out, int out_size, void* d_ws, size_t ws_size,
                              hipStream_t stream) {
  const float* q    = (const float*)d_in[0];
  const float* bank = (const float*)d_in[1];
  const float* Wk   = (const float*)d_in[2];
  const float* bk   = (const float*)d_in[3];
  const float* Wv   = (const float*)d_in[4];
  const float* bv   = (const float*)d_in[5];
  float* out = (float*)d_out;
  char* ws = (char*)d_ws;

  size_t off = 0;
  f16_t*  qf    = (f16_t*)(ws + off);  off += (size_t)NQ * QDIM * 2;
  f16_t*  kf    = (f16_t*)(ws + off);  off += (size_t)KS * QDIM * 2;
  bf16_t* VT    = (bf16_t*)(ws + off); off += (size_t)HDIM * KS * 2;
  f16_t*  bkf16 = (f16_t*)(ws + off);  off += (size_t)KS * HDIM * 2;   // bank f16
  bf16_t* bkbf  = (bf16_t*)(ws + off); off += (size_t)KS * HDIM * 2;   // bank bf16
  f16_t*  wkf   = (f16_t*)(ws + off);  off += (size_t)QDIM * HDIM * 2;
  bf16_t* wvt   = (bf16_t*)(ws + off); off += (size_t)HDIM * HDIM * 2;
  float*  lpart = (float*)(ws + off);  off += (size_t)NQ * 256 * 4;

  // R=2048: P chunk (134MB) + VT (67MB) + out-chunk stay ~L3-resident
  int R = 2048;
  while (R > 256 && off + (size_t)R * KS * 2 > ws_size) R >>= 1;
  bf16_t* P = (bf16_t*)(ws + off);
  const int Rm = R / 256;

  hipMemsetAsync(d_out, 0, (size_t)out_size * sizeof(float), stream);

  prep_q   <<<NQ * QDIM / 4 / 256, 256, 0, stream>>>(q, qf);
  prep_bank<<<KS * HDIM / 4 / 256, 256, 0, stream>>>(bank, bkf16, bkbf);
  prep_wk  <<<QDIM * HDIM / 256, 256, 0, stream>>>(Wk, wkf);
  prep_wv  <<<HDIM * HDIM / 256, 256, 0, stream>>>(Wv, wvt);
  keys_gemm    <<<dim3(QDIM / 128, KS / 128), 256, 0, stream>>>(bkf16, wkf, bk, kf);
  values_gemm_t<<<dim3(HDIM / 128, KS / 128), 256, 0, stream>>>(bkbf, wvt, bv, VT);

  for (int row0 = 0; row0 < NQ; row0 += R) {
    score_fused_8p<<<(KS / 256) * Rm, 512, 0, stream>>>(qf, kf, P, lpart, row0, Rm);
    pv_gemm_8p    <<<8 * Rm * (HDIM / 256), 512, 0, stream>>>(P, VT, out, row0, Rm);
  }
  normalize<<<NQ, 256, 0, stream>>>(lpart, out);
}

// Round 2
// 1367.395 us; speedup vs baseline: 1.2021x; 1.0600x over previous
//
#include <hip/hip_runtime.h>
#include <cstdint>
#include <cstddef>

// ---------------------------------------------------------------------------
// ParameterizedKnowledgeStore: out = softmax(q @ (bank@Wk+bk)^T) @ (bank@Wv+bv)
// B*S=8192 queries (Q=512), K=32768 knowledge rows, H=1024.
// R7: score + pv on 256x256 / BK=64 / 8-wave 8-phase counted-vmcnt schedule.
// R8: ONE barrier per phase (WAR-safe with vmcnt(6) discipline, verified per
//     half-tile), no explicit lgkmcnt(0) (compiler emits fine-grained waits),
//     pv epilogue atomics -> per-z slab stores (alias dead bank-f16 buffer)
//     + fused reduce+normalize per chunk. normalize/memset removed.
// ---------------------------------------------------------------------------

typedef __bf16 bf16_t;
typedef __bf16 bf16x4 __attribute__((ext_vector_type(4)));
typedef __bf16 bf16x8 __attribute__((ext_vector_type(8)));
typedef _Float16 f16_t;
typedef _Float16 f16x4 __attribute__((ext_vector_type(4)));
typedef _Float16 f16x8 __attribute__((ext_vector_type(8)));
typedef float f32x4 __attribute__((ext_vector_type(4)));

#define KS   32768
#define HDIM 1024
#define QDIM 512
#define NQ   8192
#define SOFTMAX_C 90.0f

// ---------------------------------------------------------------------------
__device__ __forceinline__ void async16(const void* g, void* l) {
  __builtin_amdgcn_global_load_lds((const __attribute__((address_space(1))) void*)g,
                                   (__attribute__((address_space(3))) void*)l, 16, 0, 0);
}

// Compiler-fenced raw barrier: no vmcnt(0) drain, no memory-op motion across.
__device__ __forceinline__ void barrier_f() {
  asm volatile("" ::: "memory");
  __builtin_amdgcn_s_barrier();
  asm volatile("" ::: "memory");
}

// ---------------------------------------------------------------------------
// old 128-tile staging helper (keys/values GEMMs)
// ---------------------------------------------------------------------------
template <typename T>
__device__ __forceinline__ void stage_tile(const T* gbase, size_t ld, int k0,
                                           T* lds, int wave, int lane) {
  const int gp = ((lane & 3) ^ ((lane >> 3) & 3)) * 8;
  for (int c = wave; c < 8; c += 4) {
    const T* g = gbase + (size_t)(c * 16 + (lane >> 2)) * ld + (size_t)k0 + gp;
    async16((const void*)g, (void*)(lds + c * 512));
  }
}

// ---------------------------------------------------------------------------
// 256x256 8-phase core. Half-tile = 256 rows x 32 k (16KB), 2 loads/thread.
// LDS per half: [256][32], 16B-piece swizzle c' = c ^ ((row>>1)&3), applied on
// the global source (LDS written linearly) and on the ds_read side.
// ---------------------------------------------------------------------------
template <typename T>
__device__ __forceinline__ void stage_half(const T* gbase, size_t ld, int gk,
                                           T* ldsbase, int wave, int lane) {
#pragma unroll
  for (int g = 0; g < 2; ++g) {
    const int slot = g * 512 + wave * 64 + lane;
    const int row = slot >> 2;
    const int cx = (slot & 3) ^ ((row >> 1) & 3);
    const T* src = gbase + (size_t)row * ld + (size_t)gk + cx * 8;
    async16((const void*)src, (void*)(ldsbase + g * 4096 + wave * 512));
  }
}

struct MF16 {
  typedef f16_t T; typedef f16x8 V8;
  static __device__ __forceinline__ f32x4 mm(V8 a, V8 b, f32x4 c) {
    return __builtin_amdgcn_mfma_f32_16x16x32_f16(a, b, c, 0, 0, 0);
  }
};
struct MBF16 {
  typedef bf16_t T; typedef bf16x8 V8;
  static __device__ __forceinline__ f32x4 mm(V8 a, V8 b, f32x4 c) {
    return __builtin_amdgcn_mfma_f32_16x16x32_bf16(a, b, c, 0, 0, 0);
  }
};

// sm: 65536 elems (128KB). buf b at b*32768: A-k0 @ +0, A-k1 @ +8192,
// B-k0 @ +16384, B-k1 @ +24576.
// Phase p body: [ds_reads_p ; stage_p ; (P4: counted vmcnt) ; barrier ; MFMA_p]
// ONE barrier per phase. WAR-safety: stage_p's target region was last read in
// phase p-1, and stage_p issues only after barrier_{p-1} (all waves done).
// RAW-safety: data read in tile t was staged >=3 phases earlier and is drained
// by the vmcnt(6) at P4 of tile t-1 (newest-6 = the three t+1 halves).
template <class M>
__device__ __forceinline__ void gemm256_8p(
    const typename M::T* __restrict__ A, size_t lda,
    const typename M::T* __restrict__ B, size_t ldb,
    int kbeg, int ktiles, typename M::T* sm,
    f32x4 (&acc)[8][4], int wave, int lane) {
  typedef typename M::T T;
  typedef typename M::V8 V8;
  const int wm = wave & 1, wn = wave >> 1;
  const int qd = lane >> 4, ln = lane & 15;
  const int arow = wm * 128 + ln;
  const int brow = wn * 64 + ln;
  const int cxr = (qd ^ ((ln >> 1) & 3)) * 8;

  // prologue: T0{H0..H3}, T1{H0,H1,H2}; vmcnt(6) drains exactly T0 (8 loads)
  stage_half(B, ldb, kbeg +  0, sm + 16384, wave, lane);
  stage_half(B, ldb, kbeg + 32, sm + 24576, wave, lane);
  stage_half(A, lda, kbeg +  0, sm +     0, wave, lane);
  stage_half(A, lda, kbeg + 32, sm +  8192, wave, lane);
  stage_half(B, ldb, kbeg + 64, sm + 32768 + 16384, wave, lane);
  stage_half(B, ldb, kbeg + 96, sm + 32768 + 24576, wave, lane);
  stage_half(A, lda, kbeg + 64, sm + 32768, wave, lane);
  asm volatile("s_waitcnt vmcnt(6)" ::: "memory");
  barrier_f();

  V8 ar[4], br0[4], br1[4];
  for (int t = 0; t < ktiles; ++t) {
    const int b = t & 1;
    T* bufA = sm + b * 32768;
    T* bufB = bufA + 16384;
    T* obufA = sm + (b ^ 1) * 32768;
    const int kt = kbeg + t * 64;
    // ---- phase 1: read A-k0(m0-3)+B-k0; stage T(t+1)H3
#pragma unroll
    for (int j = 0; j < 4; ++j) br0[j] = *(const V8*)&bufB[(brow + j * 16) * 32 + cxr];
#pragma unroll
    for (int i = 0; i < 4; ++i) ar[i] = *(const V8*)&bufA[(arow + i * 16) * 32 + cxr];
    if (t + 1 < ktiles) stage_half(A, lda, kt + 96, obufA + 8192, wave, lane);
    barrier_f();
    __builtin_amdgcn_s_setprio(1);
#pragma unroll
    for (int i = 0; i < 4; ++i)
#pragma unroll
      for (int j = 0; j < 4; ++j) acc[i][j] = M::mm(ar[i], br0[j], acc[i][j]);
    __builtin_amdgcn_s_setprio(0);
    // ---- phase 2: read A-k1(m0-3)+B-k1; stage T(t+2)H0
#pragma unroll
    for (int j = 0; j < 4; ++j) br1[j] = *(const V8*)&bufB[8192 + (brow + j * 16) * 32 + cxr];
#pragma unroll
    for (int i = 0; i < 4; ++i) ar[i] = *(const V8*)&bufA[8192 + (arow + i * 16) * 32 + cxr];
    if (t + 2 < ktiles) stage_half(B, ldb, kt + 128, bufB, wave, lane);
    barrier_f();
    __builtin_amdgcn_s_setprio(1);
#pragma unroll
    for (int i = 0; i < 4; ++i)
#pragma unroll
      for (int j = 0; j < 4; ++j) acc[i][j] = M::mm(ar[i], br1[j], acc[i][j]);
    __builtin_amdgcn_s_setprio(0);
    // ---- phase 3: read A-k0(m4-7); B-k0 from regs; stage T(t+2)H1
#pragma unroll
    for (int i = 0; i < 4; ++i) ar[i] = *(const V8*)&bufA[(arow + 64 + i * 16) * 32 + cxr];
    if (t + 2 < ktiles) stage_half(B, ldb, kt + 160, bufB + 8192, wave, lane);
    barrier_f();
    __builtin_amdgcn_s_setprio(1);
#pragma unroll
    for (int i = 0; i < 4; ++i)
#pragma unroll
      for (int j = 0; j < 4; ++j) acc[4 + i][j] = M::mm(ar[i], br0[j], acc[4 + i][j]);
    __builtin_amdgcn_s_setprio(0);
    // ---- phase 4: read A-k1(m4-7); B-k1 from regs; stage T(t+2)H2; counted vmcnt
#pragma unroll
    for (int i = 0; i < 4; ++i) ar[i] = *(const V8*)&bufA[8192 + (arow + 64 + i * 16) * 32 + cxr];
    if (t + 2 < ktiles) stage_half(A, lda, kt + 128, bufA, wave, lane);
    if (t + 2 < ktiles) { asm volatile("s_waitcnt vmcnt(6)" ::: "memory"); }
    else                { asm volatile("s_waitcnt vmcnt(0)" ::: "memory"); }
    barrier_f();
    __builtin_amdgcn_s_setprio(1);
#pragma unroll
    for (int i = 0; i < 4; ++i)
#pragma unroll
      for (int j = 0; j < 4; ++j) acc[4 + i][j] = M::mm(ar[i], br1[j], acc[4 + i][j]);
    __builtin_amdgcn_s_setprio(0);
  }
}

// ---------------------------------------------------------------------------
// prep kernels
// ---------------------------------------------------------------------------
__global__ __launch_bounds__(256) void prep_q(const float* __restrict__ q,
                                              f16_t* __restrict__ qf) {
  int g = blockIdx.x * 256 + threadIdx.x;
  float4 v = *(const float4*)(q + (size_t)g * 4);
  f16x4 h;
  h[0] = (f16_t)v.x; h[1] = (f16_t)v.y; h[2] = (f16_t)v.z; h[3] = (f16_t)v.w;
  *(f16x4*)(qf + (size_t)g * 4) = h;
}

__global__ __launch_bounds__(256) void prep_bank(const float* __restrict__ bank,
                                                 f16_t* __restrict__ bh,
                                                 bf16_t* __restrict__ bb) {
  size_t g = (size_t)blockIdx.x * 256 + threadIdx.x;
  float4 v = *(const float4*)(bank + g * 4);
  f16x4 h;
  h[0] = (f16_t)v.x; h[1] = (f16_t)v.y; h[2] = (f16_t)v.z; h[3] = (f16_t)v.w;
  *(f16x4*)(bh + g * 4) = h;
  bf16x4 b;
  b[0] = (bf16_t)v.x; b[1] = (bf16_t)v.y; b[2] = (bf16_t)v.z; b[3] = (bf16_t)v.w;
  *(bf16x4*)(bb + g * 4) = b;
}

__global__ __launch_bounds__(256) void prep_wk(const float* __restrict__ Wk,
                                               f16_t* __restrict__ WkTf) {
  int t = blockIdx.x * 256 + threadIdx.x;
  int n = t >> 10, k = t & 1023;
  WkTf[t] = (f16_t)Wk[(size_t)k * QDIM + n];
}

__global__ __launch_bounds__(256) void prep_wv(const float* __restrict__ Wv,
                                               bf16_t* __restrict__ WvT) {
  int t = blockIdx.x * 256 + threadIdx.x;
  int n = t >> 10, k = t & 1023;
  WvT[t] = (bf16_t)(Wv[(size_t)k * HDIM + n]);
}

// ---------------------------------------------------------------------------
// keys GEMM (fp16, all-async): kf[32768][512] = bank_f16 @ WkTf^T + bk
// ---------------------------------------------------------------------------
__global__ __launch_bounds__(256) void keys_gemm(const f16_t* __restrict__ bh,
                                                 const f16_t* __restrict__ WkTf,
                                                 const float* __restrict__ bk,
                                                 f16_t* __restrict__ kf) {
  __shared__ alignas(16) f16_t lA[128 * 32];
  __shared__ alignas(16) f16_t lB[128 * 32];
  const int tid = threadIdx.x, lane = tid & 63, wave = tid >> 6;
  const int wm = wave & 1, wn = wave >> 1;
  const int qd = lane >> 4, ln = lane & 15;
  const int m0 = blockIdx.y * 128;
  const int n0 = blockIdx.x * 128;
  const int kqs = ((qd ^ ((ln >> 1) & 3)) << 3);
  f32x4 acc[4][4] = {};
  for (int k0 = 0; k0 < HDIM; k0 += 32) {
    stage_tile(bh + (size_t)m0 * HDIM, HDIM, k0, lA, wave, lane);
    stage_tile(WkTf + (size_t)n0 * HDIM, HDIM, k0, lB, wave, lane);
    __syncthreads();
    f16x8 af[4], bfr[4];
#pragma unroll
    for (int i = 0; i < 4; i++)
      af[i] = *(const f16x8*)&lA[(wm * 64 + i * 16 + ln) * 32 + kqs];
#pragma unroll
    for (int j = 0; j < 4; j++)
      bfr[j] = *(const f16x8*)&lB[(wn * 64 + j * 16 + ln) * 32 + kqs];
#pragma unroll
    for (int i = 0; i < 4; i++)
#pragma unroll
      for (int j = 0; j < 4; j++)
        acc[i][j] = __builtin_amdgcn_mfma_f32_16x16x32_f16(af[i], bfr[j], acc[i][j], 0, 0, 0);
    __syncthreads();
  }
#pragma unroll
  for (int j = 0; j < 4; j++) {
    const int cc = n0 + wn * 64 + j * 16 + ln;
    const float bkc = bk[cc];
#pragma unroll
    for (int i = 0; i < 4; i++) {
      const int rr = m0 + wm * 64 + i * 16 + qd * 4;
#pragma unroll
      for (int r = 0; r < 4; r++)
        kf[(size_t)(rr + r) * QDIM + cc] = (f16_t)(acc[i][j][r] + bkc);
    }
  }
}

// ---------------------------------------------------------------------------
// values GEMM (bf16, all-async, transposed out): VT[h][k] = (bank@Wv+bv)^T
// ---------------------------------------------------------------------------
__global__ __launch_bounds__(256) void values_gemm_t(const bf16_t* __restrict__ bb,
                                                     const bf16_t* __restrict__ WvT,
                                                     const float* __restrict__ bv,
                                                     bf16_t* __restrict__ VT) {
  __shared__ alignas(16) bf16_t lA[128 * 32];
  __shared__ alignas(16) bf16_t lB[128 * 32];
  const int tid = threadIdx.x, lane = tid & 63, wave = tid >> 6;
  const int wm = wave & 1, wn = wave >> 1;
  const int qd = lane >> 4, ln = lane & 15;
  const int m0 = blockIdx.x * 128;
  const int n0 = blockIdx.y * 128;
  const int kqs = ((qd ^ ((ln >> 1) & 3)) << 3);
  f32x4 acc[4][4] = {};
  for (int k0 = 0; k0 < HDIM; k0 += 32) {
    stage_tile(WvT + (size_t)m0 * HDIM, HDIM, k0, lA, wave, lane);
    stage_tile(bb + (size_t)n0 * HDIM, HDIM, k0, lB, wave, lane);
    __syncthreads();
    bf16x8 af[4], bfr[4];
#pragma unroll
    for (int i = 0; i < 4; i++)
      af[i] = *(const bf16x8*)&lA[(wm * 64 + i * 16 + ln) * 32 + kqs];
#pragma unroll
    for (int j = 0; j < 4; j++)
      bfr[j] = *(const bf16x8*)&lB[(wn * 64 + j * 16 + ln) * 32 + kqs];
#pragma unroll
    for (int i = 0; i < 4; i++)
#pragma unroll
      for (int j = 0; j < 4; j++)
        acc[i][j] = __builtin_amdgcn_mfma_f32_16x16x32_bf16(af[i], bfr[j], acc[i][j], 0, 0, 0);
    __syncthreads();
  }
#pragma unroll
  for (int i = 0; i < 4; i++) {
#pragma unroll
    for (int r = 0; r < 4; r++) {
      const int hh = m0 + wm * 64 + i * 16 + qd * 4 + r;
      const float bvc = bv[hh];
#pragma unroll
      for (int j = 0; j < 4; j++) {
        const int cc = n0 + wn * 64 + j * 16 + ln;
        VT[(size_t)hh * KS + cc] = (bf16_t)(acc[i][j][r] + bvc);
      }
    }
  }
}

// ---------------------------------------------------------------------------
// fused score GEMM (fp16, K=512, 256x256 8-phase) + softmax-exp epilogue.
// lpart[row][nblock], nblock = KS/256 = 128 per row.
// ---------------------------------------------------------------------------
__global__ __launch_bounds__(512, 2) void score_fused_8p(
    const f16_t* __restrict__ qf, const f16_t* __restrict__ kf,
    bf16_t* __restrict__ P, float* __restrict__ lpart, int row0, int mtiles) {
  __shared__ alignas(16) f16_t sm[65536];
  const int tid = threadIdx.x, lane = tid & 63, wave = tid >> 6;
  const int bid = blockIdx.x;
  const int logical = (bid & 7) * ((int)gridDim.x >> 3) + (bid >> 3);
  const int mt_ = logical % mtiles;   // co-resident: 8m share kf panels in L2
  const int nt_ = logical / mtiles;
  const int m0 = mt_ * 256, n0 = nt_ * 256;
  f32x4 acc[8][4] = {};
  gemm256_8p<MF16>(qf + (size_t)(row0 + m0) * QDIM, QDIM,
                   kf + (size_t)n0 * QDIM, QDIM, 0, QDIM / 64, sm, acc, wave, lane);

  const int wm = wave & 1, wn = wave >> 1;
  const int qd = lane >> 4, ln = lane & 15;
  float* ls = (float*)sm;
  if (tid < 256) ls[tid] = 0.f;
  __syncthreads();
  float rsum[8][4];
#pragma unroll
  for (int ii = 0; ii < 8; ++ii) {
    const int rr = m0 + wm * 128 + ii * 16 + qd * 4;
#pragma unroll
    for (int r = 0; r < 4; ++r) rsum[ii][r] = 0.f;
#pragma unroll
    for (int j = 0; j < 4; ++j) {
      const int cc = n0 + wn * 64 + j * 16 + ln;
#pragma unroll
      for (int r = 0; r < 4; ++r) {
        float e = __expf(acc[ii][j][r] - SOFTMAX_C);
        bf16_t pb = (bf16_t)e;
        P[(size_t)(rr + r) * KS + cc] = pb;
        rsum[ii][r] += (float)pb;
      }
    }
  }
#pragma unroll
  for (int ii = 0; ii < 8; ++ii)
#pragma unroll
    for (int r = 0; r < 4; ++r) {
      float s = rsum[ii][r];
#pragma unroll
      for (int off = 1; off < 16; off <<= 1) s += __shfl_xor(s, off);
      if (ln == 0) atomicAdd(&ls[wm * 128 + ii * 16 + qd * 4 + r], s);
    }
  __syncthreads();
  if (tid < 256)
    lpart[(size_t)(row0 + m0 + tid) * (KS / 256) + nt_] = ls[tid];
}

// ---------------------------------------------------------------------------
// PV GEMM (bf16, 256x256 8-phase): slab[z][row][h] = sum over z's k-span.
// Plain coalesced stores (no atomics); z = bid % zsplit keeps each k-span's
// blocks on one XCD (zsplit multiple of 8).
// ---------------------------------------------------------------------------
__global__ __launch_bounds__(512, 2) void pv_gemm_8p(
    const bf16_t* __restrict__ P, const bf16_t* __restrict__ VT,
    float* __restrict__ slab, int mtiles, int zsplit) {
  __shared__ alignas(16) bf16_t sm[65536];
  const int tid = threadIdx.x, lane = tid & 63, wave = tid >> 6;
  const int bid = blockIdx.x;
  const int z = bid % zsplit;
  const int idx = bid / zsplit;
  const int mt_ = idx % mtiles;
  const int nt_ = idx / mtiles;
  const int m0 = mt_ * 256;          // chunk-relative q rows
  const int n0 = nt_ * 256;          // h cols
  const int kspan = KS / zsplit;
  const int kbeg = z * kspan;
  f32x4 acc[8][4] = {};
  gemm256_8p<MBF16>(P + (size_t)m0 * KS, KS,
                    VT + (size_t)n0 * KS, KS, kbeg, kspan / 64, sm, acc, wave, lane);

  const int wm = wave & 1, wn = wave >> 1;
  const int qd = lane >> 4, ln = lane & 15;
  float* slabz = slab + (size_t)z * (size_t)(mtiles * 256) * HDIM;
#pragma unroll
  for (int j = 0; j < 4; ++j) {
    const int cc = n0 + wn * 64 + j * 16 + ln;
#pragma unroll
    for (int ii = 0; ii < 8; ++ii) {
      const int rb = m0 + wm * 128 + ii * 16 + qd * 4;
#pragma unroll
      for (int r = 0; r < 4; ++r)
        slabz[(size_t)(rb + r) * HDIM + cc] = acc[ii][j][r];
    }
  }
}

// ---------------------------------------------------------------------------
// fused reduce over z-slabs + softmax normalization. One block per chunk row.
// ---------------------------------------------------------------------------
__global__ __launch_bounds__(256) void reduce_norm(const float* __restrict__ slab,
                                                   const float* __restrict__ lpart,
                                                   float* __restrict__ Out,
                                                   int row0, int R, int zsplit) {
  const int row = blockIdx.x;
  float s = (threadIdx.x < 128) ? lpart[(size_t)(row0 + row) * (KS / 256) + threadIdx.x] : 0.f;
#pragma unroll
  for (int off = 32; off; off >>= 1) s += __shfl_xor(s, off);
  __shared__ float red[4];
  if ((threadIdx.x & 63) == 0) red[threadIdx.x >> 6] = s;
  __syncthreads();
  const float linv = 1.0f / (red[0] + red[1] + red[2] + red[3]);
  const float* p = slab + (size_t)row * HDIM + threadIdx.x * 4;
  float4 a = make_float4(0.f, 0.f, 0.f, 0.f);
  for (int zz = 0; zz < zsplit; ++zz) {
    float4 v = *(const float4*)(p + (size_t)zz * R * HDIM);
    a.x += v.x; a.y += v.y; a.z += v.z; a.w += v.w;
  }
  a.x *= linv; a.y *= linv; a.z *= linv; a.w *= linv;
  *(float4*)(Out + (size_t)(row0 + row) * HDIM + threadIdx.x * 4) = a;
}

// ---------------------------------------------------------------------------
extern "C" void kernel_launch(void* const* d_in, const int* in_sizes, int n_in,
                              void* d_out, int out_size, void* d_ws, size_t ws_size,
                              hipStream_t stream) {
  const float* q    = (const float*)d_in[0];
  const float* bank = (const float*)d_in[1];
  const float* Wk   = (const float*)d_in[2];
  const float* bk   = (const float*)d_in[3];
  const float* Wv   = (const float*)d_in[4];
  const float* bv   = (const float*)d_in[5];
  float* out = (float*)d_out;
  char* ws = (char*)d_ws;

  size_t off = 0;
  f16_t*  qf    = (f16_t*)(ws + off);  off += (size_t)NQ * QDIM * 2;
  f16_t*  kf    = (f16_t*)(ws + off);  off += (size_t)KS * QDIM * 2;
  bf16_t* VT    = (bf16_t*)(ws + off); off += (size_t)HDIM * KS * 2;
  f16_t*  bkf16 = (f16_t*)(ws + off);  off += (size_t)KS * HDIM * 2;   // bank f16; dead after keys_gemm -> reused as slab
  bf16_t* bkbf  = (bf16_t*)(ws + off); off += (size_t)KS * HDIM * 2;   // bank bf16
  f16_t*  wkf   = (f16_t*)(ws + off);  off += (size_t)QDIM * HDIM * 2;
  bf16_t* wvt   = (bf16_t*)(ws + off); off += (size_t)HDIM * HDIM * 2;
  float*  lpart = (float*)(ws + off);  off += (size_t)NQ * 256 * 4;

  // R=2048: P chunk (134MB) + VT (67MB) + slabs stay ~L3-resident
  int R = 2048;
  while (R > 256 && off + (size_t)R * KS * 2 > ws_size) R >>= 1;
  bf16_t* P = (bf16_t*)(ws + off);
  const int Rm = R / 256;

  // pv k-split: zsplit*R = 16384 => slab = zsplit*R*HDIM*4B = 64MB = |bkf16|
  int zsplit = 16384 / R;
  if (zsplit < 8) zsplit = 8;
  if (zsplit > 64) zsplit = 64;
  float* slab = (float*)bkf16;       // aliased; keys_gemm finished before pv

  prep_q   <<<NQ * QDIM / 4 / 256, 256, 0, stream>>>(q, qf);
  prep_bank<<<KS * HDIM / 4 / 256, 256, 0, stream>>>(bank, bkf16, bkbf);
  prep_wk  <<<QDIM * HDIM / 256, 256, 0, stream>>>(Wk, wkf);
  prep_wv  <<<HDIM * HDIM / 256, 256, 0, stream>>>(Wv, wvt);
  keys_gemm    <<<dim3(QDIM / 128, KS / 128), 256, 0, stream>>>(bkf16, wkf, bk, kf);
  values_gemm_t<<<dim3(HDIM / 128, KS / 128), 256, 0, stream>>>(bkbf, wvt, bv, VT);

  for (int row0 = 0; row0 < NQ; row0 += R) {
    score_fused_8p<<<(KS / 256) * Rm, 512, 0, stream>>>(qf, kf, P, lpart, row0, Rm);
    pv_gemm_8p    <<<zsplit * Rm * (HDIM / 256), 512, 0, stream>>>(P, VT, slab, Rm, zsplit);
    reduce_norm   <<<R, 256, 0, stream>>>(slab, lpart, out, row0, R, zsplit);
  }
}

// Round 3
// 1323.209 us; speedup vs baseline: 1.2423x; 1.0334x over previous
//
#include <hip/hip_runtime.h>
#include <cstdint>
#include <cstddef>

// ---------------------------------------------------------------------------
// ParameterizedKnowledgeStore: out = softmax(q @ (bank@Wk+bk)^T) @ (bank@Wv+bv)
// B*S=8192 queries (Q=512), K=32768 knowledge rows, H=1024.
// R7: score + pv on 256x256 / BK=64 / 8-wave 8-phase counted-vmcnt schedule.
// R8: one barrier per phase; pv slab stores + fused reduce_norm.
// R9: SWAPPED-OPERAND epilogues everywhere (A<->B so the contiguous output
//     dim lands in the acc register index): P stores 2B->8B (4x fewer
//     instrs), pv stores 4B->16B, kf/VT stores 2B->8B; softmax row-reduce
//     2 shuffles instead of 4. keys/values ported to the 256^2 8-phase core.
// ---------------------------------------------------------------------------

typedef __bf16 bf16_t;
typedef __bf16 bf16x4 __attribute__((ext_vector_type(4)));
typedef __bf16 bf16x8 __attribute__((ext_vector_type(8)));
typedef _Float16 f16_t;
typedef _Float16 f16x4 __attribute__((ext_vector_type(4)));
typedef _Float16 f16x8 __attribute__((ext_vector_type(8)));
typedef float f32x4 __attribute__((ext_vector_type(4)));

#define KS   32768
#define HDIM 1024
#define QDIM 512
#define NQ   8192
#define SOFTMAX_C 90.0f

// ---------------------------------------------------------------------------
__device__ __forceinline__ void async16(const void* g, void* l) {
  __builtin_amdgcn_global_load_lds((const __attribute__((address_space(1))) void*)g,
                                   (__attribute__((address_space(3))) void*)l, 16, 0, 0);
}

// Compiler-fenced raw barrier: no vmcnt(0) drain, no memory-op motion across.
__device__ __forceinline__ void barrier_f() {
  asm volatile("" ::: "memory");
  __builtin_amdgcn_s_barrier();
  asm volatile("" ::: "memory");
}

// ---------------------------------------------------------------------------
// 256x256 8-phase core. Half-tile = 256 rows x 32 k (16KB), 2 loads/thread.
// LDS per half: [256][32], 16B-piece swizzle c' = c ^ ((row>>1)&3), applied on
// the global source (LDS written linearly) and on the ds_read side.
// ---------------------------------------------------------------------------
template <typename T>
__device__ __forceinline__ void stage_half(const T* gbase, size_t ld, int gk,
                                           T* ldsbase, int wave, int lane) {
#pragma unroll
  for (int g = 0; g < 2; ++g) {
    const int slot = g * 512 + wave * 64 + lane;
    const int row = slot >> 2;
    const int cx = (slot & 3) ^ ((row >> 1) & 3);
    const T* src = gbase + (size_t)row * ld + (size_t)gk + cx * 8;
    async16((const void*)src, (void*)(ldsbase + g * 4096 + wave * 512));
  }
}

struct MF16 {
  typedef f16_t T; typedef f16x8 V8;
  static __device__ __forceinline__ f32x4 mm(V8 a, V8 b, f32x4 c) {
    return __builtin_amdgcn_mfma_f32_16x16x32_f16(a, b, c, 0, 0, 0);
  }
};
struct MBF16 {
  typedef bf16_t T; typedef bf16x8 V8;
  static __device__ __forceinline__ f32x4 mm(V8 a, V8 b, f32x4 c) {
    return __builtin_amdgcn_mfma_f32_16x16x32_bf16(a, b, c, 0, 0, 0);
  }
};

// sm: 65536 elems (128KB). buf b at b*32768: A-k0 @ +0, A-k1 @ +8192,
// B-k0 @ +16384, B-k1 @ +24576.
// Phase p body: [ds_reads_p ; stage_p ; (P4: counted vmcnt) ; barrier ; MFMA_p]
// ONE barrier per phase; vmcnt(6) once per K-tile (never 0 in main loop).
// acc[ii][j]: ii = A-dim fragment (wm half, 128 rows), j = B-dim (wn, 64).
template <class M>
__device__ __forceinline__ void gemm256_8p(
    const typename M::T* __restrict__ A, size_t lda,
    const typename M::T* __restrict__ B, size_t ldb,
    int kbeg, int ktiles, typename M::T* sm,
    f32x4 (&acc)[8][4], int wave, int lane) {
  typedef typename M::T T;
  typedef typename M::V8 V8;
  const int wm = wave & 1, wn = wave >> 1;
  const int qd = lane >> 4, ln = lane & 15;
  const int arow = wm * 128 + ln;
  const int brow = wn * 64 + ln;
  const int cxr = (qd ^ ((ln >> 1) & 3)) * 8;

  // prologue: T0{H0..H3}, T1{H0,H1,H2}; vmcnt(6) drains exactly T0 (8 loads)
  stage_half(B, ldb, kbeg +  0, sm + 16384, wave, lane);
  stage_half(B, ldb, kbeg + 32, sm + 24576, wave, lane);
  stage_half(A, lda, kbeg +  0, sm +     0, wave, lane);
  stage_half(A, lda, kbeg + 32, sm +  8192, wave, lane);
  stage_half(B, ldb, kbeg + 64, sm + 32768 + 16384, wave, lane);
  stage_half(B, ldb, kbeg + 96, sm + 32768 + 24576, wave, lane);
  stage_half(A, lda, kbeg + 64, sm + 32768, wave, lane);
  asm volatile("s_waitcnt vmcnt(6)" ::: "memory");
  barrier_f();

  V8 ar[4], br0[4], br1[4];
  for (int t = 0; t < ktiles; ++t) {
    const int b = t & 1;
    T* bufA = sm + b * 32768;
    T* bufB = bufA + 16384;
    T* obufA = sm + (b ^ 1) * 32768;
    const int kt = kbeg + t * 64;
    // ---- phase 1: read A-k0(m0-3)+B-k0; stage T(t+1)H3
#pragma unroll
    for (int j = 0; j < 4; ++j) br0[j] = *(const V8*)&bufB[(brow + j * 16) * 32 + cxr];
#pragma unroll
    for (int i = 0; i < 4; ++i) ar[i] = *(const V8*)&bufA[(arow + i * 16) * 32 + cxr];
    if (t + 1 < ktiles) stage_half(A, lda, kt + 96, obufA + 8192, wave, lane);
    barrier_f();
    __builtin_amdgcn_s_setprio(1);
#pragma unroll
    for (int i = 0; i < 4; ++i)
#pragma unroll
      for (int j = 0; j < 4; ++j) acc[i][j] = M::mm(ar[i], br0[j], acc[i][j]);
    __builtin_amdgcn_s_setprio(0);
    // ---- phase 2: read A-k1(m0-3)+B-k1; stage T(t+2)H0
#pragma unroll
    for (int j = 0; j < 4; ++j) br1[j] = *(const V8*)&bufB[8192 + (brow + j * 16) * 32 + cxr];
#pragma unroll
    for (int i = 0; i < 4; ++i) ar[i] = *(const V8*)&bufA[8192 + (arow + i * 16) * 32 + cxr];
    if (t + 2 < ktiles) stage_half(B, ldb, kt + 128, bufB, wave, lane);
    barrier_f();
    __builtin_amdgcn_s_setprio(1);
#pragma unroll
    for (int i = 0; i < 4; ++i)
#pragma unroll
      for (int j = 0; j < 4; ++j) acc[i][j] = M::mm(ar[i], br1[j], acc[i][j]);
    __builtin_amdgcn_s_setprio(0);
    // ---- phase 3: read A-k0(m4-7); B-k0 from regs; stage T(t+2)H1
#pragma unroll
    for (int i = 0; i < 4; ++i) ar[i] = *(const V8*)&bufA[(arow + 64 + i * 16) * 32 + cxr];
    if (t + 2 < ktiles) stage_half(B, ldb, kt + 160, bufB + 8192, wave, lane);
    barrier_f();
    __builtin_amdgcn_s_setprio(1);
#pragma unroll
    for (int i = 0; i < 4; ++i)
#pragma unroll
      for (int j = 0; j < 4; ++j) acc[4 + i][j] = M::mm(ar[i], br0[j], acc[4 + i][j]);
    __builtin_amdgcn_s_setprio(0);
    // ---- phase 4: read A-k1(m4-7); B-k1 from regs; stage T(t+2)H2; counted vmcnt
#pragma unroll
    for (int i = 0; i < 4; ++i) ar[i] = *(const V8*)&bufA[8192 + (arow + 64 + i * 16) * 32 + cxr];
    if (t + 2 < ktiles) stage_half(A, lda, kt + 128, bufA, wave, lane);
    if (t + 2 < ktiles) { asm volatile("s_waitcnt vmcnt(6)" ::: "memory"); }
    else                { asm volatile("s_waitcnt vmcnt(0)" ::: "memory"); }
    barrier_f();
    __builtin_amdgcn_s_setprio(1);
#pragma unroll
    for (int i = 0; i < 4; ++i)
#pragma unroll
      for (int j = 0; j < 4; ++j) acc[4 + i][j] = M::mm(ar[i], br1[j], acc[4 + i][j]);
    __builtin_amdgcn_s_setprio(0);
  }
}

// ---------------------------------------------------------------------------
// prep kernels
// ---------------------------------------------------------------------------
__global__ __launch_bounds__(256) void prep_q(const float* __restrict__ q,
                                              f16_t* __restrict__ qf) {
  int g = blockIdx.x * 256 + threadIdx.x;
  float4 v = *(const float4*)(q + (size_t)g * 4);
  f16x4 h;
  h[0] = (f16_t)v.x; h[1] = (f16_t)v.y; h[2] = (f16_t)v.z; h[3] = (f16_t)v.w;
  *(f16x4*)(qf + (size_t)g * 4) = h;
}

__global__ __launch_bounds__(256) void prep_bank(const float* __restrict__ bank,
                                                 f16_t* __restrict__ bh,
                                                 bf16_t* __restrict__ bb) {
  size_t g = (size_t)blockIdx.x * 256 + threadIdx.x;
  float4 v = *(const float4*)(bank + g * 4);
  f16x4 h;
  h[0] = (f16_t)v.x; h[1] = (f16_t)v.y; h[2] = (f16_t)v.z; h[3] = (f16_t)v.w;
  *(f16x4*)(bh + g * 4) = h;
  bf16x4 b;
  b[0] = (bf16_t)v.x; b[1] = (bf16_t)v.y; b[2] = (bf16_t)v.z; b[3] = (bf16_t)v.w;
  *(bf16x4*)(bb + g * 4) = b;
}

__global__ __launch_bounds__(256) void prep_wk(const float* __restrict__ Wk,
                                               f16_t* __restrict__ WkTf) {
  int t = blockIdx.x * 256 + threadIdx.x;
  int n = t >> 10, k = t & 1023;
  WkTf[t] = (f16_t)Wk[(size_t)k * QDIM + n];
}

__global__ __launch_bounds__(256) void prep_wv(const float* __restrict__ Wv,
                                               bf16_t* __restrict__ WvT) {
  int t = blockIdx.x * 256 + threadIdx.x;
  int n = t >> 10, k = t & 1023;
  WvT[t] = (bf16_t)(Wv[(size_t)k * HDIM + n]);
}

// ---------------------------------------------------------------------------
// keys GEMM (fp16, 8-phase, swapped): C[keycol][bank] = WkTf x bh
// kf[bank][keycol]: per-thread 4 consecutive keycols -> 8B stores.
// ---------------------------------------------------------------------------
__global__ __launch_bounds__(512, 2) void keys_gemm_8p(
    const f16_t* __restrict__ bh, const f16_t* __restrict__ WkTf,
    const float* __restrict__ bk, f16_t* __restrict__ kf) {
  __shared__ alignas(16) f16_t sm[65536];
  const int tid = threadIdx.x, lane = tid & 63, wave = tid >> 6;
  const int mt = blockIdx.x & 1;        // keycol tile (A side)
  const int nt = blockIdx.x >> 1;       // bank tile (B side)
  f32x4 acc[8][4] = {};
  gemm256_8p<MF16>(WkTf + (size_t)(mt * 256) * HDIM, HDIM,
                   bh + (size_t)(nt * 256) * HDIM, HDIM, 0, HDIM / 64, sm, acc, wave, lane);
  const int wm = wave & 1, wn = wave >> 1;
  const int qd = lane >> 4, ln = lane & 15;
#pragma unroll
  for (int ii = 0; ii < 8; ++ii) {
    const int kcb = mt * 256 + wm * 128 + ii * 16 + qd * 4;
    const float4 b4 = *(const float4*)&bk[kcb];
#pragma unroll
    for (int j = 0; j < 4; ++j) {
      const int bank = nt * 256 + wn * 64 + j * 16 + ln;
      f16x4 o;
      o[0] = (f16_t)(acc[ii][j][0] + b4.x);
      o[1] = (f16_t)(acc[ii][j][1] + b4.y);
      o[2] = (f16_t)(acc[ii][j][2] + b4.z);
      o[3] = (f16_t)(acc[ii][j][3] + b4.w);
      *(f16x4*)&kf[(size_t)bank * QDIM + kcb] = o;
    }
  }
}

// ---------------------------------------------------------------------------
// values GEMM (bf16, 8-phase, swapped): C[k][h] = bank x WvT
// VT[h][k]: per-thread 4 consecutive k -> 8B stores.
// ---------------------------------------------------------------------------
__global__ __launch_bounds__(512, 2) void values_gemm_8p(
    const bf16_t* __restrict__ bb, const bf16_t* __restrict__ WvT,
    const float* __restrict__ bv, bf16_t* __restrict__ VT) {
  __shared__ alignas(16) bf16_t sm[65536];
  const int tid = threadIdx.x, lane = tid & 63, wave = tid >> 6;
  const int nt = blockIdx.x & 3;        // h tile (B side)
  const int mt = blockIdx.x >> 2;       // knowledge tile (A side)
  f32x4 acc[8][4] = {};
  gemm256_8p<MBF16>(bb + (size_t)(mt * 256) * HDIM, HDIM,
                    WvT + (size_t)(nt * 256) * HDIM, HDIM, 0, HDIM / 64, sm, acc, wave, lane);
  const int wm = wave & 1, wn = wave >> 1;
  const int qd = lane >> 4, ln = lane & 15;
#pragma unroll
  for (int j = 0; j < 4; ++j) {
    const int hh = nt * 256 + wn * 64 + j * 16 + ln;
    const float bvh = bv[hh];
#pragma unroll
    for (int ii = 0; ii < 8; ++ii) {
      const int kcb = mt * 256 + wm * 128 + ii * 16 + qd * 4;
      bf16x4 o;
      o[0] = (bf16_t)(acc[ii][j][0] + bvh);
      o[1] = (bf16_t)(acc[ii][j][1] + bvh);
      o[2] = (bf16_t)(acc[ii][j][2] + bvh);
      o[3] = (bf16_t)(acc[ii][j][3] + bvh);
      *(bf16x4*)&VT[(size_t)hh * KS + kcb] = o;
    }
  }
}

// ---------------------------------------------------------------------------
// fused score GEMM (fp16, K=512, 8-phase, swapped: C[kcol][qrow]) + softmax.
// P[qrow][kcol]: per-thread 4 consecutive kcols -> 8B stores; row-reduce is
// 2 shuffles (xor 16,32) + 4 LDS atomics. lpart width = KS/256 = 128.
// ---------------------------------------------------------------------------
__global__ __launch_bounds__(512, 2) void score_fused_8p(
    const f16_t* __restrict__ qf, const f16_t* __restrict__ kf,
    bf16_t* __restrict__ P, float* __restrict__ lpart, int row0, int mtiles) {
  __shared__ alignas(16) f16_t sm[65536];
  const int tid = threadIdx.x, lane = tid & 63, wave = tid >> 6;
  const int bid = blockIdx.x;
  const int logical = (bid & 7) * ((int)gridDim.x >> 3) + (bid >> 3);
  const int mt_ = logical % mtiles;   // q tile (B side now)
  const int nt_ = logical / mtiles;   // k tile (A side now)
  const int q0 = mt_ * 256, k0 = nt_ * 256;
  f32x4 acc[8][4] = {};
  gemm256_8p<MF16>(kf + (size_t)k0 * QDIM, QDIM,
                   qf + (size_t)(row0 + q0) * QDIM, QDIM, 0, QDIM / 64, sm, acc, wave, lane);

  const int wm = wave & 1, wn = wave >> 1;
  const int qd = lane >> 4, ln = lane & 15;
  float* ls = (float*)sm;
  if (tid < 256) ls[tid] = 0.f;
  __syncthreads();
  float rsum[4] = {0.f, 0.f, 0.f, 0.f};
#pragma unroll
  for (int ii = 0; ii < 8; ++ii) {
    const int kcb = k0 + wm * 128 + ii * 16 + qd * 4;
#pragma unroll
    for (int j = 0; j < 4; ++j) {
      const int qr = q0 + wn * 64 + j * 16 + ln;
      bf16x4 pb;
      float s4 = 0.f;
#pragma unroll
      for (int r = 0; r < 4; ++r) {
        float e = __expf(acc[ii][j][r] - SOFTMAX_C);
        pb[r] = (bf16_t)e;
        s4 += (float)pb[r];
      }
      *(bf16x4*)&P[(size_t)qr * KS + kcb] = pb;
      rsum[j] += s4;
    }
  }
#pragma unroll
  for (int j = 0; j < 4; ++j) {
    float s = rsum[j];
    s += __shfl_xor(s, 16);
    s += __shfl_xor(s, 32);
    if (qd == 0) atomicAdd(&ls[wn * 64 + j * 16 + ln], s);
  }
  __syncthreads();
  if (tid < 256)
    lpart[(size_t)(row0 + q0 + tid) * (KS / 256) + nt_] = ls[tid];
}

// ---------------------------------------------------------------------------
// PV GEMM (bf16, 8-phase, swapped: C[h][qrow]): slab[z][qrow][h] over k-span.
// Per-thread 4 consecutive h -> 16B f32x4 stores.
// ---------------------------------------------------------------------------
__global__ __launch_bounds__(512, 2) void pv_gemm_8p(
    const bf16_t* __restrict__ P, const bf16_t* __restrict__ VT,
    float* __restrict__ slab, int mtiles, int zsplit) {
  __shared__ alignas(16) bf16_t sm[65536];
  const int tid = threadIdx.x, lane = tid & 63, wave = tid >> 6;
  const int bid = blockIdx.x;
  const int z = bid % zsplit;
  const int idx = bid / zsplit;
  const int mt_ = idx % mtiles;       // q tile (B side now)
  const int nt_ = idx / mtiles;       // h tile (A side now)
  const int q0 = mt_ * 256;
  const int h0 = nt_ * 256;
  const int kspan = KS / zsplit;
  const int kbeg = z * kspan;
  f32x4 acc[8][4] = {};
  gemm256_8p<MBF16>(VT + (size_t)h0 * KS, KS,
                    P + (size_t)q0 * KS, KS, kbeg, kspan / 64, sm, acc, wave, lane);

  const int wm = wave & 1, wn = wave >> 1;
  const int qd = lane >> 4, ln = lane & 15;
  float* slabz = slab + (size_t)z * (size_t)(mtiles * 256) * HDIM;
#pragma unroll
  for (int j = 0; j < 4; ++j) {
    const int qr = q0 + wn * 64 + j * 16 + ln;
#pragma unroll
    for (int ii = 0; ii < 8; ++ii) {
      const int hcb = h0 + wm * 128 + ii * 16 + qd * 4;
      *(f32x4*)&slabz[(size_t)qr * HDIM + hcb] = acc[ii][j];
    }
  }
}

// ---------------------------------------------------------------------------
// fused reduce over z-slabs + softmax normalization. One block per chunk row.
// ---------------------------------------------------------------------------
__global__ __launch_bounds__(256) void reduce_norm(const float* __restrict__ slab,
                                                   const float* __restrict__ lpart,
                                                   float* __restrict__ Out,
                                                   int row0, int R, int zsplit) {
  const int row = blockIdx.x;
  float s = (threadIdx.x < 128) ? lpart[(size_t)(row0 + row) * (KS / 256) + threadIdx.x] : 0.f;
#pragma unroll
  for (int off = 32; off; off >>= 1) s += __shfl_xor(s, off);
  __shared__ float red[4];
  if ((threadIdx.x & 63) == 0) red[threadIdx.x >> 6] = s;
  __syncthreads();
  const float linv = 1.0f / (red[0] + red[1] + red[2] + red[3]);
  const float* p = slab + (size_t)row * HDIM + threadIdx.x * 4;
  float4 a = make_float4(0.f, 0.f, 0.f, 0.f);
  for (int zz = 0; zz < zsplit; ++zz) {
    float4 v = *(const float4*)(p + (size_t)zz * R * HDIM);
    a.x += v.x; a.y += v.y; a.z += v.z; a.w += v.w;
  }
  a.x *= linv; a.y *= linv; a.z *= linv; a.w *= linv;
  *(float4*)(Out + (size_t)(row0 + row) * HDIM + threadIdx.x * 4) = a;
}

// ---------------------------------------------------------------------------
extern "C" void kernel_launch(void* const* d_in, const int* in_sizes, int n_in,
                              void* d_out, int out_size, void* d_ws, size_t ws_size,
                              hipStream_t stream) {
  const float* q    = (const float*)d_in[0];
  const float* bank = (const float*)d_in[1];
  const float* Wk   = (const float*)d_in[2];
  const float* bk   = (const float*)d_in[3];
  const float* Wv   = (const float*)d_in[4];
  const float* bv   = (const float*)d_in[5];
  float* out = (float*)d_out;
  char* ws = (char*)d_ws;

  size_t off = 0;
  f16_t*  qf    = (f16_t*)(ws + off);  off += (size_t)NQ * QDIM * 2;
  f16_t*  kf    = (f16_t*)(ws + off);  off += (size_t)KS * QDIM * 2;
  bf16_t* VT    = (bf16_t*)(ws + off); off += (size_t)HDIM * KS * 2;
  f16_t*  bkf16 = (f16_t*)(ws + off);  off += (size_t)KS * HDIM * 2;   // bank f16; dead after keys -> slab
  bf16_t* bkbf  = (bf16_t*)(ws + off); off += (size_t)KS * HDIM * 2;   // bank bf16
  f16_t*  wkf   = (f16_t*)(ws + off);  off += (size_t)QDIM * HDIM * 2;
  bf16_t* wvt   = (bf16_t*)(ws + off); off += (size_t)HDIM * HDIM * 2;
  float*  lpart = (float*)(ws + off);  off += (size_t)NQ * 256 * 4;

  // R=2048: P chunk (134MB) + VT (67MB) + slabs stay ~L3-resident
  int R = 2048;
  while (R > 256 && off + (size_t)R * KS * 2 > ws_size) R >>= 1;
  bf16_t* P = (bf16_t*)(ws + off);
  const int Rm = R / 256;

  // pv k-split: zsplit*R = 16384 => slab = zsplit*R*HDIM*4B = 64MB = |bkf16|
  int zsplit = 16384 / R;
  if (zsplit < 8) zsplit = 8;
  if (zsplit > 64) zsplit = 64;
  float* slab = (float*)bkf16;       // aliased; keys_gemm finished before pv

  prep_q   <<<NQ * QDIM / 4 / 256, 256, 0, stream>>>(q, qf);
  prep_bank<<<KS * HDIM / 4 / 256, 256, 0, stream>>>(bank, bkf16, bkbf);
  prep_wk  <<<QDIM * HDIM / 256, 256, 0, stream>>>(Wk, wkf);
  prep_wv  <<<HDIM * HDIM / 256, 256, 0, stream>>>(Wv, wvt);
  keys_gemm_8p  <<<(QDIM / 256) * (KS / 256), 512, 0, stream>>>(bkf16, wkf, bk, kf);
  values_gemm_8p<<<(HDIM / 256) * (KS / 256), 512, 0, stream>>>(bkbf, wvt, bv, VT);

  for (int row0 = 0; row0 < NQ; row0 += R) {
    score_fused_8p<<<(KS / 256) * Rm, 512, 0, stream>>>(qf, kf, P, lpart, row0, Rm);
    pv_gemm_8p    <<<zsplit * Rm * (HDIM / 256), 512, 0, stream>>>(P, VT, slab, Rm, zsplit);
    reduce_norm   <<<R, 256, 0, stream>>>(slab, lpart, out, row0, R, zsplit);
  }
}

// Round 4
// 1308.211 us; speedup vs baseline: 1.2565x; 1.0115x over previous
//
#include <hip/hip_runtime.h>
#include <cstdint>
#include <cstddef>

// ---------------------------------------------------------------------------
// ParameterizedKnowledgeStore: out = softmax(q @ (bank@Wk+bk)^T) @ (bank@Wv+bv)
// B*S=8192 queries (Q=512), K=32768 knowledge rows, H=1024.
// R7: 256x256 / BK=64 / 8-wave 8-phase counted-vmcnt schedule (all GEMMs).
// R8: one barrier per phase; pv slab stores + fused reduce_norm.
// R9: swapped-operand epilogues (contiguous out dim in acc reg index).
// R10: LDS-read/MFMA overlap: double-buffered fragment register sets
//      (arA/arB, brA/brB) + reads hoisted one phase early (issued post-
//      barrier, interleaved with the PREVIOUS phase's MFMA cluster). Each
//      ds_read's lgkm-wait lands a full phase after issue; LDS pipe drains
//      under the matrix pipe instead of serializing with it.
// ---------------------------------------------------------------------------

typedef __bf16 bf16_t;
typedef __bf16 bf16x4 __attribute__((ext_vector_type(4)));
typedef __bf16 bf16x8 __attribute__((ext_vector_type(8)));
typedef _Float16 f16_t;
typedef _Float16 f16x4 __attribute__((ext_vector_type(4)));
typedef _Float16 f16x8 __attribute__((ext_vector_type(8)));
typedef float f32x4 __attribute__((ext_vector_type(4)));

#define KS   32768
#define HDIM 1024
#define QDIM 512
#define NQ   8192
#define SOFTMAX_C 90.0f

// ---------------------------------------------------------------------------
__device__ __forceinline__ void async16(const void* g, void* l) {
  __builtin_amdgcn_global_load_lds((const __attribute__((address_space(1))) void*)g,
                                   (__attribute__((address_space(3))) void*)l, 16, 0, 0);
}

// Compiler-fenced raw barrier: no vmcnt(0) drain, no memory-op motion across.
__device__ __forceinline__ void barrier_f() {
  asm volatile("" ::: "memory");
  __builtin_amdgcn_s_barrier();
  asm volatile("" ::: "memory");
}

// ---------------------------------------------------------------------------
// 256x256 8-phase core. Half-tile = 256 rows x 32 k (16KB), 2 loads/thread.
// LDS per half: [256][32], 16B-piece swizzle c' = c ^ ((row>>1)&3), applied on
// the global source (LDS written linearly) and on the ds_read side.
// ---------------------------------------------------------------------------
template <typename T>
__device__ __forceinline__ void stage_half(const T* gbase, size_t ld, int gk,
                                           T* ldsbase, int wave, int lane) {
#pragma unroll
  for (int g = 0; g < 2; ++g) {
    const int slot = g * 512 + wave * 64 + lane;
    const int row = slot >> 2;
    const int cx = (slot & 3) ^ ((row >> 1) & 3);
    const T* src = gbase + (size_t)row * ld + (size_t)gk + cx * 8;
    async16((const void*)src, (void*)(ldsbase + g * 4096 + wave * 512));
  }
}

struct MF16 {
  typedef f16_t T; typedef f16x8 V8;
  static __device__ __forceinline__ f32x4 mm(V8 a, V8 b, f32x4 c) {
    return __builtin_amdgcn_mfma_f32_16x16x32_f16(a, b, c, 0, 0, 0);
  }
};
struct MBF16 {
  typedef bf16_t T; typedef bf16x8 V8;
  static __device__ __forceinline__ f32x4 mm(V8 a, V8 b, f32x4 c) {
    return __builtin_amdgcn_mfma_f32_16x16x32_bf16(a, b, c, 0, 0, 0);
  }
};

// sm: 65536 elems (128KB). buf b at b*32768: A-k0 @ +0, A-k1 @ +8192,
// B-k0 @ +16384, B-k1 @ +24576.
// Phase p: [stage_p ; (P4: counted vmcnt) ; barrier ; reads_{p+1} ; MFMA_p]
// reads_{p+1} write the fragment set MFMA_p does NOT use (arA/arB alternate;
// brA used P1+P3, brB used P2+P4; t+1-P1 set loaded at P4 post-vmcnt-barrier).
// RAW: every read's consuming MFMA is one full phase later (lgkm off critical
// path). WAR windows (stage write vs last LDS read of region): each separated
// by >=1 barrier + vmem latency -- verified per region, same as R8.
template <class M>
__device__ __forceinline__ void gemm256_8p(
    const typename M::T* __restrict__ A, size_t lda,
    const typename M::T* __restrict__ B, size_t ldb,
    int kbeg, int ktiles, typename M::T* sm,
    f32x4 (&acc)[8][4], int wave, int lane) {
  typedef typename M::T T;
  typedef typename M::V8 V8;
  const int wm = wave & 1, wn = wave >> 1;
  const int qd = lane >> 4, ln = lane & 15;
  const int arow = wm * 128 + ln;
  const int brow = wn * 64 + ln;
  const int cxr = (qd ^ ((ln >> 1) & 3)) * 8;

  // prologue: T0{H0..H3}, T1{H0,H1,H2}; vmcnt(6) drains exactly T0 (8 loads)
  stage_half(B, ldb, kbeg +  0, sm + 16384, wave, lane);
  stage_half(B, ldb, kbeg + 32, sm + 24576, wave, lane);
  stage_half(A, lda, kbeg +  0, sm +     0, wave, lane);
  stage_half(A, lda, kbeg + 32, sm +  8192, wave, lane);
  stage_half(B, ldb, kbeg + 64, sm + 32768 + 16384, wave, lane);
  stage_half(B, ldb, kbeg + 96, sm + 32768 + 24576, wave, lane);
  stage_half(A, lda, kbeg + 64, sm + 32768, wave, lane);
  asm volatile("s_waitcnt vmcnt(6)" ::: "memory");
  barrier_f();   // all waves' T0 stages drained -> T0-P1 reads safe below

  V8 arA[4], arB[4], brA[4], brB[4];
#pragma unroll
  for (int j = 0; j < 4; ++j) brA[j] = *(const V8*)&sm[16384 + (brow + j * 16) * 32 + cxr];
#pragma unroll
  for (int i = 0; i < 4; ++i) arA[i] = *(const V8*)&sm[(arow + i * 16) * 32 + cxr];

  for (int t = 0; t < ktiles; ++t) {
    const int b = t & 1;
    T* bufA = sm + b * 32768;
    T* bufB = bufA + 16384;
    T* obufA = sm + (b ^ 1) * 32768;
    T* obufB = obufA + 16384;
    const int kt = kbeg + t * 64;
    // ---- P1: stage A(t+1)k1; reads for P2 (k1 m0-3 + B k1); MFMA k0 m0-3
    if (t + 1 < ktiles) stage_half(A, lda, kt + 96, obufA + 8192, wave, lane);
    barrier_f();
#pragma unroll
    for (int j = 0; j < 4; ++j) brB[j] = *(const V8*)&bufB[8192 + (brow + j * 16) * 32 + cxr];
#pragma unroll
    for (int i = 0; i < 4; ++i) arB[i] = *(const V8*)&bufA[8192 + (arow + i * 16) * 32 + cxr];
    __builtin_amdgcn_s_setprio(1);
#pragma unroll
    for (int i = 0; i < 4; ++i)
#pragma unroll
      for (int j = 0; j < 4; ++j) acc[i][j] = M::mm(arA[i], brA[j], acc[i][j]);
    __builtin_amdgcn_s_setprio(0);
    // ---- P2: stage B(t+2)k0; reads for P3 (k0 m4-7); MFMA k1 m0-3
    if (t + 2 < ktiles) stage_half(B, ldb, kt + 128, bufB, wave, lane);
    barrier_f();
#pragma unroll
    for (int i = 0; i < 4; ++i) arA[i] = *(const V8*)&bufA[(arow + 64 + i * 16) * 32 + cxr];
    __builtin_amdgcn_s_setprio(1);
#pragma unroll
    for (int i = 0; i < 4; ++i)
#pragma unroll
      for (int j = 0; j < 4; ++j) acc[i][j] = M::mm(arB[i], brB[j], acc[i][j]);
    __builtin_amdgcn_s_setprio(0);
    // ---- P3: stage B(t+2)k1; reads for P4 (k1 m4-7); MFMA k0 m4-7 (brA reused)
    if (t + 2 < ktiles) stage_half(B, ldb, kt + 160, bufB + 8192, wave, lane);
    barrier_f();
#pragma unroll
    for (int i = 0; i < 4; ++i) arB[i] = *(const V8*)&bufA[8192 + (arow + 64 + i * 16) * 32 + cxr];
    __builtin_amdgcn_s_setprio(1);
#pragma unroll
    for (int i = 0; i < 4; ++i)
#pragma unroll
      for (int j = 0; j < 4; ++j) acc[4 + i][j] = M::mm(arA[i], brA[j], acc[4 + i][j]);
    __builtin_amdgcn_s_setprio(0);
    // ---- P4: stage A(t+2)k0; counted vmcnt; reads for T(t+1)-P1; MFMA k1 m4-7
    if (t + 2 < ktiles) stage_half(A, lda, kt + 128, bufA, wave, lane);
    if (t + 2 < ktiles) { asm volatile("s_waitcnt vmcnt(6)" ::: "memory"); }
    else                { asm volatile("s_waitcnt vmcnt(0)" ::: "memory"); }
    barrier_f();   // t+1 halves drained (all waves) -> t+1-P1 reads safe
    if (t + 1 < ktiles) {
#pragma unroll
      for (int j = 0; j < 4; ++j) brA[j] = *(const V8*)&obufB[(brow + j * 16) * 32 + cxr];
#pragma unroll
      for (int i = 0; i < 4; ++i) arA[i] = *(const V8*)&obufA[(arow + i * 16) * 32 + cxr];
    }
    __builtin_amdgcn_s_setprio(1);
#pragma unroll
    for (int i = 0; i < 4; ++i)
#pragma unroll
      for (int j = 0; j < 4; ++j) acc[4 + i][j] = M::mm(arB[i], brB[j], acc[4 + i][j]);
    __builtin_amdgcn_s_setprio(0);
  }
}

// ---------------------------------------------------------------------------
// prep kernels
// ---------------------------------------------------------------------------
__global__ __launch_bounds__(256) void prep_q(const float* __restrict__ q,
                                              f16_t* __restrict__ qf) {
  int g = blockIdx.x * 256 + threadIdx.x;
  float4 v = *(const float4*)(q + (size_t)g * 4);
  f16x4 h;
  h[0] = (f16_t)v.x; h[1] = (f16_t)v.y; h[2] = (f16_t)v.z; h[3] = (f16_t)v.w;
  *(f16x4*)(qf + (size_t)g * 4) = h;
}

__global__ __launch_bounds__(256) void prep_bank(const float* __restrict__ bank,
                                                 f16_t* __restrict__ bh,
                                                 bf16_t* __restrict__ bb) {
  size_t g = (size_t)blockIdx.x * 256 + threadIdx.x;
  float4 v = *(const float4*)(bank + g * 4);
  f16x4 h;
  h[0] = (f16_t)v.x; h[1] = (f16_t)v.y; h[2] = (f16_t)v.z; h[3] = (f16_t)v.w;
  *(f16x4*)(bh + g * 4) = h;
  bf16x4 b;
  b[0] = (bf16_t)v.x; b[1] = (bf16_t)v.y; b[2] = (bf16_t)v.z; b[3] = (bf16_t)v.w;
  *(bf16x4*)(bb + g * 4) = b;
}

__global__ __launch_bounds__(256) void prep_wk(const float* __restrict__ Wk,
                                               f16_t* __restrict__ WkTf) {
  int t = blockIdx.x * 256 + threadIdx.x;
  int n = t >> 10, k = t & 1023;
  WkTf[t] = (f16_t)Wk[(size_t)k * QDIM + n];
}

__global__ __launch_bounds__(256) void prep_wv(const float* __restrict__ Wv,
                                               bf16_t* __restrict__ WvT) {
  int t = blockIdx.x * 256 + threadIdx.x;
  int n = t >> 10, k = t & 1023;
  WvT[t] = (bf16_t)(Wv[(size_t)k * HDIM + n]);
}

// ---------------------------------------------------------------------------
// keys GEMM (fp16, 8-phase, swapped): C[keycol][bank] = WkTf x bh
// kf[bank][keycol]: per-thread 4 consecutive keycols -> 8B stores.
// ---------------------------------------------------------------------------
__global__ __launch_bounds__(512, 2) void keys_gemm_8p(
    const f16_t* __restrict__ bh, const f16_t* __restrict__ WkTf,
    const float* __restrict__ bk, f16_t* __restrict__ kf) {
  __shared__ alignas(16) f16_t sm[65536];
  const int tid = threadIdx.x, lane = tid & 63, wave = tid >> 6;
  const int mt = blockIdx.x & 1;        // keycol tile (A side)
  const int nt = blockIdx.x >> 1;       // bank tile (B side)
  f32x4 acc[8][4] = {};
  gemm256_8p<MF16>(WkTf + (size_t)(mt * 256) * HDIM, HDIM,
                   bh + (size_t)(nt * 256) * HDIM, HDIM, 0, HDIM / 64, sm, acc, wave, lane);
  const int wm = wave & 1, wn = wave >> 1;
  const int qd = lane >> 4, ln = lane & 15;
#pragma unroll
  for (int ii = 0; ii < 8; ++ii) {
    const int kcb = mt * 256 + wm * 128 + ii * 16 + qd * 4;
    const float4 b4 = *(const float4*)&bk[kcb];
#pragma unroll
    for (int j = 0; j < 4; ++j) {
      const int bank = nt * 256 + wn * 64 + j * 16 + ln;
      f16x4 o;
      o[0] = (f16_t)(acc[ii][j][0] + b4.x);
      o[1] = (f16_t)(acc[ii][j][1] + b4.y);
      o[2] = (f16_t)(acc[ii][j][2] + b4.z);
      o[3] = (f16_t)(acc[ii][j][3] + b4.w);
      *(f16x4*)&kf[(size_t)bank * QDIM + kcb] = o;
    }
  }
}

// ---------------------------------------------------------------------------
// values GEMM (bf16, 8-phase, swapped): C[k][h] = bank x WvT
// VT[h][k]: per-thread 4 consecutive k -> 8B stores.
// ---------------------------------------------------------------------------
__global__ __launch_bounds__(512, 2) void values_gemm_8p(
    const bf16_t* __restrict__ bb, const bf16_t* __restrict__ WvT,
    const float* __restrict__ bv, bf16_t* __restrict__ VT) {
  __shared__ alignas(16) bf16_t sm[65536];
  const int tid = threadIdx.x, lane = tid & 63, wave = tid >> 6;
  const int nt = blockIdx.x & 3;        // h tile (B side)
  const int mt = blockIdx.x >> 2;       // knowledge tile (A side)
  f32x4 acc[8][4] = {};
  gemm256_8p<MBF16>(bb + (size_t)(mt * 256) * HDIM, HDIM,
                    WvT + (size_t)(nt * 256) * HDIM, HDIM, 0, HDIM / 64, sm, acc, wave, lane);
  const int wm = wave & 1, wn = wave >> 1;
  const int qd = lane >> 4, ln = lane & 15;
#pragma unroll
  for (int j = 0; j < 4; ++j) {
    const int hh = nt * 256 + wn * 64 + j * 16 + ln;
    const float bvh = bv[hh];
#pragma unroll
    for (int ii = 0; ii < 8; ++ii) {
      const int kcb = mt * 256 + wm * 128 + ii * 16 + qd * 4;
      bf16x4 o;
      o[0] = (bf16_t)(acc[ii][j][0] + bvh);
      o[1] = (bf16_t)(acc[ii][j][1] + bvh);
      o[2] = (bf16_t)(acc[ii][j][2] + bvh);
      o[3] = (bf16_t)(acc[ii][j][3] + bvh);
      *(bf16x4*)&VT[(size_t)hh * KS + kcb] = o;
    }
  }
}

// ---------------------------------------------------------------------------
// fused score GEMM (fp16, K=512, 8-phase, swapped: C[kcol][qrow]) + softmax.
// P[qrow][kcol]: per-thread 4 consecutive kcols -> 8B stores; row-reduce is
// 2 shuffles (xor 16,32) + 4 LDS atomics. lpart width = KS/256 = 128.
// ---------------------------------------------------------------------------
__global__ __launch_bounds__(512, 2) void score_fused_8p(
    const f16_t* __restrict__ qf, const f16_t* __restrict__ kf,
    bf16_t* __restrict__ P, float* __restrict__ lpart, int row0, int mtiles) {
  __shared__ alignas(16) f16_t sm[65536];
  const int tid = threadIdx.x, lane = tid & 63, wave = tid >> 6;
  const int bid = blockIdx.x;
  const int logical = (bid & 7) * ((int)gridDim.x >> 3) + (bid >> 3);
  const int mt_ = logical % mtiles;   // q tile (B side now)
  const int nt_ = logical / mtiles;   // k tile (A side now)
  const int q0 = mt_ * 256, k0 = nt_ * 256;
  f32x4 acc[8][4] = {};
  gemm256_8p<MF16>(kf + (size_t)k0 * QDIM, QDIM,
                   qf + (size_t)(row0 + q0) * QDIM, QDIM, 0, QDIM / 64, sm, acc, wave, lane);

  const int wm = wave & 1, wn = wave >> 1;
  const int qd = lane >> 4, ln = lane & 15;
  float* ls = (float*)sm;
  if (tid < 256) ls[tid] = 0.f;
  __syncthreads();
  float rsum[4] = {0.f, 0.f, 0.f, 0.f};
#pragma unroll
  for (int ii = 0; ii < 8; ++ii) {
    const int kcb = k0 + wm * 128 + ii * 16 + qd * 4;
#pragma unroll
    for (int j = 0; j < 4; ++j) {
      const int qr = q0 + wn * 64 + j * 16 + ln;
      bf16x4 pb;
      float s4 = 0.f;
#pragma unroll
      for (int r = 0; r < 4; ++r) {
        float e = __expf(acc[ii][j][r] - SOFTMAX_C);
        pb[r] = (bf16_t)e;
        s4 += (float)pb[r];
      }
      *(bf16x4*)&P[(size_t)qr * KS + kcb] = pb;
      rsum[j] += s4;
    }
  }
#pragma unroll
  for (int j = 0; j < 4; ++j) {
    float s = rsum[j];
    s += __shfl_xor(s, 16);
    s += __shfl_xor(s, 32);
    if (qd == 0) atomicAdd(&ls[wn * 64 + j * 16 + ln], s);
  }
  __syncthreads();
  if (tid < 256)
    lpart[(size_t)(row0 + q0 + tid) * (KS / 256) + nt_] = ls[tid];
}

// ---------------------------------------------------------------------------
// PV GEMM (bf16, 8-phase, swapped: C[h][qrow]): slab[z][qrow][h] over k-span.
// Per-thread 4 consecutive h -> 16B f32x4 stores.
// ---------------------------------------------------------------------------
__global__ __launch_bounds__(512, 2) void pv_gemm_8p(
    const bf16_t* __restrict__ P, const bf16_t* __restrict__ VT,
    float* __restrict__ slab, int mtiles, int zsplit) {
  __shared__ alignas(16) bf16_t sm[65536];
  const int tid = threadIdx.x, lane = tid & 63, wave = tid >> 6;
  const int bid = blockIdx.x;
  const int z = bid % zsplit;
  const int idx = bid / zsplit;
  const int mt_ = idx % mtiles;       // q tile (B side now)
  const int nt_ = idx / mtiles;       // h tile (A side now)
  const int q0 = mt_ * 256;
  const int h0 = nt_ * 256;
  const int kspan = KS / zsplit;
  const int kbeg = z * kspan;
  f32x4 acc[8][4] = {};
  gemm256_8p<MBF16>(VT + (size_t)h0 * KS, KS,
                    P + (size_t)q0 * KS, KS, kbeg, kspan / 64, sm, acc, wave, lane);

  const int wm = wave & 1, wn = wave >> 1;
  const int qd = lane >> 4, ln = lane & 15;
  float* slabz = slab + (size_t)z * (size_t)(mtiles * 256) * HDIM;
#pragma unroll
  for (int j = 0; j < 4; ++j) {
    const int qr = q0 + wn * 64 + j * 16 + ln;
#pragma unroll
    for (int ii = 0; ii < 8; ++ii) {
      const int hcb = h0 + wm * 128 + ii * 16 + qd * 4;
      *(f32x4*)&slabz[(size_t)qr * HDIM + hcb] = acc[ii][j];
    }
  }
}

// ---------------------------------------------------------------------------
// fused reduce over z-slabs + softmax normalization. One block per chunk row.
// ---------------------------------------------------------------------------
__global__ __launch_bounds__(256) void reduce_norm(const float* __restrict__ slab,
                                                   const float* __restrict__ lpart,
                                                   float* __restrict__ Out,
                                                   int row0, int R, int zsplit) {
  const int row = blockIdx.x;
  float s = (threadIdx.x < 128) ? lpart[(size_t)(row0 + row) * (KS / 256) + threadIdx.x] : 0.f;
#pragma unroll
  for (int off = 32; off; off >>= 1) s += __shfl_xor(s, off);
  __shared__ float red[4];
  if ((threadIdx.x & 63) == 0) red[threadIdx.x >> 6] = s;
  __syncthreads();
  const float linv = 1.0f / (red[0] + red[1] + red[2] + red[3]);
  const float* p = slab + (size_t)row * HDIM + threadIdx.x * 4;
  float4 a = make_float4(0.f, 0.f, 0.f, 0.f);
  for (int zz = 0; zz < zsplit; ++zz) {
    float4 v = *(const float4*)(p + (size_t)zz * R * HDIM);
    a.x += v.x; a.y += v.y; a.z += v.z; a.w += v.w;
  }
  a.x *= linv; a.y *= linv; a.z *= linv; a.w *= linv;
  *(float4*)(Out + (size_t)(row0 + row) * HDIM + threadIdx.x * 4) = a;
}

// ---------------------------------------------------------------------------
extern "C" void kernel_launch(void* const* d_in, const int* in_sizes, int n_in,
                              void* d_out, int out_size, void* d_ws, size_t ws_size,
                              hipStream_t stream) {
  const float* q    = (const float*)d_in[0];
  const float* bank = (const float*)d_in[1];
  const float* Wk   = (const float*)d_in[2];
  const float* bk   = (const float*)d_in[3];
  const float* Wv   = (const float*)d_in[4];
  const float* bv   = (const float*)d_in[5];
  float* out = (float*)d_out;
  char* ws = (char*)d_ws;

  size_t off = 0;
  f16_t*  qf    = (f16_t*)(ws + off);  off += (size_t)NQ * QDIM * 2;
  f16_t*  kf    = (f16_t*)(ws + off);  off += (size_t)KS * QDIM * 2;
  bf16_t* VT    = (bf16_t*)(ws + off); off += (size_t)HDIM * KS * 2;
  f16_t*  bkf16 = (f16_t*)(ws + off);  off += (size_t)KS * HDIM * 2;   // bank f16; dead after keys -> slab
  bf16_t* bkbf  = (bf16_t*)(ws + off); off += (size_t)KS * HDIM * 2;   // bank bf16
  f16_t*  wkf   = (f16_t*)(ws + off);  off += (size_t)QDIM * HDIM * 2;
  bf16_t* wvt   = (bf16_t*)(ws + off); off += (size_t)HDIM * HDIM * 2;
  float*  lpart = (float*)(ws + off);  off += (size_t)NQ * 256 * 4;

  // R=2048: P chunk (134MB) + VT (67MB) + slabs stay ~L3-resident
  int R = 2048;
  while (R > 256 && off + (size_t)R * KS * 2 > ws_size) R >>= 1;
  bf16_t* P = (bf16_t*)(ws + off);
  const int Rm = R / 256;

  // pv k-split: zsplit*R = 16384 => slab = zsplit*R*HDIM*4B = 64MB = |bkf16|
  int zsplit = 16384 / R;
  if (zsplit < 8) zsplit = 8;
  if (zsplit > 64) zsplit = 64;
  float* slab = (float*)bkf16;       // aliased; keys_gemm finished before pv

  prep_q   <<<NQ * QDIM / 4 / 256, 256, 0, stream>>>(q, qf);
  prep_bank<<<KS * HDIM / 4 / 256, 256, 0, stream>>>(bank, bkf16, bkbf);
  prep_wk  <<<QDIM * HDIM / 256, 256, 0, stream>>>(Wk, wkf);
  prep_wv  <<<HDIM * HDIM / 256, 256, 0, stream>>>(Wv, wvt);
  keys_gemm_8p  <<<(QDIM / 256) * (KS / 256), 512, 0, stream>>>(bkf16, wkf, bk, kf);
  values_gemm_8p<<<(HDIM / 256) * (KS / 256), 512, 0, stream>>>(bkbf, wvt, bv, VT);

  for (int row0 = 0; row0 < NQ; row0 += R) {
    score_fused_8p<<<(KS / 256) * Rm, 512, 0, stream>>>(qf, kf, P, lpart, row0, Rm);
    pv_gemm_8p    <<<zsplit * Rm * (HDIM / 256), 512, 0, stream>>>(P, VT, slab, Rm, zsplit);
    reduce_norm   <<<R, 256, 0, stream>>>(slab, lpart, out, row0, R, zsplit);
  }
}